// Round 7
// baseline (225.519 us; speedup 1.0000x reference)
//
#include <hip/hip_runtime.h>
#include <stdint.h>

// SpatialAttention: B=4, C_in=256, C_out=128, N=64*64=4096
// R7 = R6 with the KV-range bug fixed: thirds are 1344/1344/1408 tokens
// (42/42/44 iters of 32), covering all 4096 keys. R6 mistakenly used
// 672/672/704 (=2048, half the range) -> absmax 5.97.
// R6 design: (1) k_proj: W pre-split to global bf16 hi/lo planes (k_wprep,
// L2-resident); B-frags loaded straight from global; X-transpose staged with
// coalesced dword loads + ds_write_b128. (2) k_flash: grid 768 = 3 blocks/CU
// (LDS 54272B). (3) merge sums 3 partials.

#define B_ 4
#define C_ 256
#define O_ 128
#define N_ 4096

#define AP 72  // proj LDS pitch (bf16 elems)
#define PP 40  // flash P-tile pitch (32 cols + pad)

typedef float v4f __attribute__((ext_vector_type(4)));
typedef short v8s __attribute__((ext_vector_type(8)));
typedef _Float16 v8h __attribute__((ext_vector_type(8)));
typedef uint32_t u32;
typedef unsigned short u16;

__device__ __forceinline__ u16 bf16_rne(float f) {
  u32 u = __builtin_bit_cast(u32, f);
  u += 0x7fffu + ((u >> 16) & 1u);
  return (u16)(u >> 16);
}
__device__ __forceinline__ float bf16_f(u16 s) {
  u32 u = ((u32)s) << 16;
  return __builtin_bit_cast(float, u);
}
__device__ __forceinline__ u16 f16_rne(float f) {
  _Float16 h = (_Float16)f;
  return __builtin_bit_cast(u16, h);
}
__device__ __forceinline__ float f16_f(u16 s) {
  return (float)__builtin_bit_cast(_Float16, s);
}
__device__ __forceinline__ v4f mfma16(v8s a, v8s b, v4f c) {
  return __builtin_amdgcn_mfma_f32_16x16x32_bf16(a, b, c, 0, 0, 0);
}
__device__ __forceinline__ v4f mfma16h(v8h a, v8h b, v4f c) {
  return __builtin_amdgcn_mfma_f32_16x16x32_f16(a, b, c, 0, 0, 0);
}
__device__ __forceinline__ void gl16(const u16* g, u16* l) {
  __builtin_amdgcn_global_load_lds(
      (const __attribute__((address_space(1))) u32*)g,
      (__attribute__((address_space(3))) u32*)l, 16, 0, 0);
}
template <int CTRL>
__device__ __forceinline__ float dppadd(float x) {
  int yi = __builtin_amdgcn_update_dpp(0, __builtin_bit_cast(int, x), CTRL,
                                       0xf, 0xf, true);
  return x + __builtin_bit_cast(float, yi);
}
__device__ __forceinline__ float sum16(float x) {
  x = dppadd<0xB1>(x);   // xor 1
  x = dppadd<0x4E>(x);   // xor 2
  x = dppadd<0x141>(x);  // xor 4 (row_half_mirror)
  x = dppadd<0x140>(x);  // xor 8 (row_mirror)
  return x;
}

// -------- W pre-split: fp32 [128][256] -> bf16 hi/lo planes (Wq and Wk) -----
__global__ __launch_bounds__(256) void k_wprep(const float* __restrict__ Wq,
                                               const float* __restrict__ Wk,
                                               u16* __restrict__ Wqh,
                                               u16* __restrict__ Wql,
                                               u16* __restrict__ Wkh,
                                               u16* __restrict__ Wkl) {
  const int inst = blockIdx.x >> 4;  // 16 blocks per matrix
  const float* src = inst ? Wk : Wq;
  u16* dh = inst ? Wkh : Wqh;
  u16* dl = inst ? Wkl : Wql;
  const int base = ((blockIdx.x & 15) * 256 + threadIdx.x) * 8;
  float4 a = ((const float4*)(src + base))[0];
  float4 c = ((const float4*)(src + base))[1];
  float v[8] = {a.x, a.y, a.z, a.w, c.x, c.y, c.z, c.w};
  u16 hh[8], ll[8];
#pragma unroll
  for (int j = 0; j < 8; j++) {
    hh[j] = bf16_rne(v[j]);
    ll[j] = bf16_rne(v[j] - bf16_f(hh[j]));
  }
  uint4 oh, ol;
  oh.x = (u32)hh[0] | ((u32)hh[1] << 16);
  oh.y = (u32)hh[2] | ((u32)hh[3] << 16);
  oh.z = (u32)hh[4] | ((u32)hh[5] << 16);
  oh.w = (u32)hh[6] | ((u32)hh[7] << 16);
  ol.x = (u32)ll[0] | ((u32)ll[1] << 16);
  ol.y = (u32)ll[2] | ((u32)ll[3] << 16);
  ol.z = (u32)ll[4] | ((u32)ll[5] << 16);
  ol.w = (u32)ll[6] | ((u32)ll[7] << 16);
  *(uint4*)(dh + base) = oh;
  *(uint4*)(dl + base) = ol;
}

// ------------- merged Q/K projection (+V cast on the K instance) ------------
// blocks 0..255: Q = p*Wq+bq -> fp16 hi/lo. 256..511: K = b*Wk+bk -> fp16 hi,
// plus bf16 cast of b into Vbf. Split-bf16 3-pass; B-frags straight from
// global W planes (8 contiguous k for fixed o == 16B vector load, L2-hot).
__global__ __launch_bounds__(256) void k_proj(
    const float* __restrict__ Xp, const float* __restrict__ Xb,
    const float* __restrict__ bq, const float* __restrict__ bk,
    const u16* __restrict__ Wqh, const u16* __restrict__ Wql,
    const u16* __restrict__ Wkh, const u16* __restrict__ Wkl,
    u16* __restrict__ Qh, u16* __restrict__ Ql, u16* __restrict__ Kh,
    u16* __restrict__ Vbf) {
  __shared__ __align__(16) short ah[64 * AP];
  __shared__ __align__(16) short al[64 * AP];
  const int tid = threadIdx.x;
  const int inst = blockIdx.x >> 8;  // block-uniform
  const float* X = inst ? Xb : Xp;
  const u16* Wh = inst ? Wkh : Wqh;
  const u16* Wl = inst ? Wkl : Wql;
  const float* bias = inst ? bk : bq;
  const int b = (blockIdx.x >> 6) & 3;
  const int n0 = (blockIdx.x & 63) << 6;
  const int w = tid >> 6, lane = tid & 63, l15 = lane & 15, quad = lane >> 4;
  v4f acc[8];
#pragma unroll
  for (int t = 0; t < 8; t++) acc[t] = (v4f){0.f, 0.f, 0.f, 0.f};

  const int sn = tid & 63;   // staging: this thread's token column
  const int scg = tid >> 6;  // and its 16-channel group

  for (int c0 = 0; c0 < C_; c0 += 64) {
    __syncthreads();
    {  // stage X^T tile: [64 tok][64 c] split hi/lo; coalesced dword loads,
       // b128 LDS writes (c contiguous per thread)
      const float* s = X + ((size_t)(b * C_ + c0 + scg * 16)) * N_ + n0 + sn;
      u16 hh[16], ll[16];
#pragma unroll
      for (int j = 0; j < 16; j++) {
        float v = s[(size_t)j * N_];
        hh[j] = bf16_rne(v);
        ll[j] = bf16_rne(v - bf16_f(hh[j]));
      }
      u32 ph[8], pl[8];
#pragma unroll
      for (int j = 0; j < 8; j++) {
        ph[j] = (u32)hh[2 * j] | ((u32)hh[2 * j + 1] << 16);
        pl[j] = (u32)ll[2 * j] | ((u32)ll[2 * j + 1] << 16);
      }
      uint4* dh = (uint4*)&ah[sn * AP + scg * 16];
      uint4* dl = (uint4*)&al[sn * AP + scg * 16];
      dh[0] = make_uint4(ph[0], ph[1], ph[2], ph[3]);
      dh[1] = make_uint4(ph[4], ph[5], ph[6], ph[7]);
      dl[0] = make_uint4(pl[0], pl[1], pl[2], pl[3]);
      dl[1] = make_uint4(pl[4], pl[5], pl[6], pl[7]);
      if (inst) {  // fused V cast (coalesced 2B stores across lanes)
#pragma unroll
        for (int j = 0; j < 16; j++)
          Vbf[((size_t)(b * C_ + c0 + scg * 16 + j)) * N_ + n0 + sn] = hh[j];
      }
    }
    __syncthreads();
#pragma unroll
    for (int s2 = 0; s2 < 2; s2++) {
      v8s a_h = *(const v8s*)&ah[(16 * w + l15) * AP + 32 * s2 + 8 * quad];
      v8s a_l = *(const v8s*)&al[(16 * w + l15) * AP + 32 * s2 + 8 * quad];
#pragma unroll
      for (int to = 0; to < 8; to++) {
        const u16* wp = Wh + (size_t)(16 * to + l15) * C_ + c0 + 32 * s2 + 8 * quad;
        const u16* wp2 = Wl + (size_t)(16 * to + l15) * C_ + c0 + 32 * s2 + 8 * quad;
        v8s b_h = *(const v8s*)wp;
        v8s b_l = *(const v8s*)wp2;
        acc[to] = mfma16(a_h, b_h, acc[to]);
        acc[to] = mfma16(a_h, b_l, acc[to]);
        acc[to] = mfma16(a_l, b_h, acc[to]);
      }
    }
  }
#pragma unroll
  for (int to = 0; to < 8; to++) {
    const int o = 16 * to + l15;
    const float bv = bias[o];
#pragma unroll
    for (int r = 0; r < 4; r++) {
      const int n = n0 + 16 * w + 4 * quad + r;  // C/D row = quad*4+reg
      float v = acc[to][r] + bv;
      const size_t idx = (size_t)(b * N_ + n) * O_ + o;
      if (!inst) {
        u16 h = f16_rne(v);
        Qh[idx] = h;
        Ql[idx] = f16_rne(v - f16_f(h));
      } else {
        Kh[idx] = f16_rne(v);
      }
    }
  }
}

// ---------------- fused flash attention (partial over a KV third) -----------
// block = (batch, 64-row Q tile, KV third 1344/1344/1408); 4 waves. QK: wave
// w owns Q rows 16w.. (2-pass fp16). PV: wave w owns channels 64w..64w+63 for
// all 64 rows; P crosses waves via LDS + raw s_barrier (lgkm wait only).
__global__ __launch_bounds__(256, 3) void k_flash(
    const u16* __restrict__ Qh, const u16* __restrict__ Ql,
    const u16* __restrict__ Khp, const u16* __restrict__ Vbf,
    u16* __restrict__ Opart, float* __restrict__ lpart) {
  // shorts: buf i at i*12288: K [32][128] fp16 @0, V [256][32] bf16 @4096
  //         P [64][PP] @24576
  __shared__ __align__(16) short smem[27136];  // 54272 B -> 3 blocks/CU
  short* Pt = smem + 24576;

  const int tid = threadIdx.x;
  const int w = tid >> 6, lane = tid & 63, l15 = lane & 15, quad = lane >> 4;
  const int bq = blockIdx.x / 3;
  const int h = blockIdx.x - bq * 3;
  const int qt = bq & 63;
  const int b = bq >> 6;
  const int n0 = qt << 6;
  const int tok0 = h * 1344;                // thirds: 1344/1344/1408 = 4096
  const int niter = (h == 2) ? 44 : 42;     // x32 tokens

  const u16* khb = Khp + (size_t)b * N_ * O_;
  const u16* vb = Vbf + (size_t)b * C_ * N_;

  // Q fragments (A-layout: row=lane&15, k=32s+8*quad+j), fp16 hi/lo
  v8h qh[4], ql[4];
  {
    const u16* qrh = Qh + (size_t)(b * N_ + n0 + 16 * w + l15) * O_;
    const u16* qrl = Ql + (size_t)(b * N_ + n0 + 16 * w + l15) * O_;
#pragma unroll
    for (int s = 0; s < 4; s++) {
      qh[s] = *(const v8h*)(qrh + 32 * s + 8 * quad);
      ql[s] = *(const v8h*)(qrl + 32 * s + 8 * quad);
    }
  }

  v4f oacc[16];  // [rw][cg]: rows 16rw+4quad+r, channels 64w+16cg+l15
#pragma unroll
  for (int t = 0; t < 16; t++) oacc[t] = (v4f){0.f, 0.f, 0.f, 0.f};
  float lstate[4] = {0.f, 0.f, 0.f, 0.f};

  auto stage = [&](int mtn, int bi) {
    const int m0n = tok0 + (mtn << 5);
    short* kd = smem + bi * 12288;
    short* vd = kd + 4096;
#pragma unroll
    for (int i = 0; i < 2; i++) {  // K fp16: 4 rows/issue, 8 rows/wave
      const int R = 8 * w + 4 * i;
      const int rl = R + (lane >> 4);
      const int cg = (lane & 15) ^ (rl & 15);
      gl16(khb + ((size_t)(m0n + rl) << 7) + (cg << 3), (u16*)(kd + (R << 7)));
    }
#pragma unroll
    for (int i = 0; i < 4; i++) {  // V bf16: 16 chan-rows/issue, 64/wave
      const int R = 64 * w + 16 * i;
      const int rl = R + (lane >> 2);
      const int cg = (lane & 3) ^ ((rl >> 1) & 3);
      gl16(vb + (size_t)rl * N_ + m0n + (cg << 3), (u16*)(vd + (R << 5)));
    }
  };

  stage(0, 0);

#pragma unroll 1
  for (int mt = 0; mt < niter; mt++) {
    const int pr = mt & 1;
    __syncthreads();  // B1: drains vmcnt(0) -> tile mt staged + visible
    if (mt + 1 < niter) stage(mt + 1, 1 - pr);
    const short* kc = smem + pr * 12288;
    const short* vc = kc + 4096;

    // QK: e = (qh+ql) . k, 2-pass fp16, two acc chains for ILP
    v4f eh[2], el[2];
#pragma unroll
    for (int t = 0; t < 2; t++) {
      eh[t] = (v4f){0.f, 0.f, 0.f, 0.f};
      el[t] = (v4f){0.f, 0.f, 0.f, 0.f};
    }
#pragma unroll
    for (int s = 0; s < 4; s++) {
#pragma unroll
      for (int t = 0; t < 2; t++) {
        const int off = ((16 * t + l15) << 7) + (((4 * s + quad) ^ l15) << 3);
        const v8h kf = *(const v8h*)&kc[off];
        eh[t] = mfma16h(qh[s], kf, eh[t]);
        el[t] = mfma16h(ql[s], kf, el[t]);
      }
    }

    // no-max softmax: p=exp(e); DPP 16-lane row sums; write P tile (shared)
#pragma unroll
    for (int r = 0; r < 4; r++) {
      float p0 = __expf(eh[0][r] + el[0][r]);
      float p1 = __expf(eh[1][r] + el[1][r]);
      lstate[r] += sum16(p0 + p1);
      Pt[(16 * w + 4 * quad + r) * PP + l15] = (short)bf16_rne(p0);
      Pt[(16 * w + 4 * quad + r) * PP + 16 + l15] = (short)bf16_rne(p1);
    }
    // B2: P handoff across waves. lgkm-only wait + raw barrier so the
    // staged prefetch (vmcnt queue) is NOT drained mid-iter.
    __builtin_amdgcn_s_waitcnt(0xC07F);  // lgkmcnt(0)
    asm volatile("s_barrier" ::: "memory");

    // PV channel-split: oacc[rw][cg] += P(rows 16rw) * V(ch 64w+16cg)
    v8s af[4];
#pragma unroll
    for (int rw = 0; rw < 4; rw++)
      af[rw] = *(const v8s*)&Pt[(16 * rw + l15) * PP + 8 * quad];
#pragma unroll
    for (int cg = 0; cg < 4; cg++) {
      const int ch = 64 * w + 16 * cg + l15;
      const int voff = (ch << 5) + ((quad ^ ((ch >> 1) & 3)) << 3);
      const v8s vf = *(const v8s*)&vc[voff];
#pragma unroll
      for (int rw = 0; rw < 4; rw++)
        oacc[rw * 4 + cg] = mfma16(af[rw], vf, oacc[rw * 4 + cg]);
    }
  }

  // epilogue: pack bf16 partial O into LDS [256][72], write l, copy out
  __syncthreads();
  u16* outx = (u16*)smem;  // pitch 72 shorts
#pragma unroll
  for (int rw = 0; rw < 4; rw++)
#pragma unroll
    for (int cg = 0; cg < 4; cg++) {
      const int ch = 64 * w + 16 * cg + l15;
      const v4f o = oacc[rw * 4 + cg];
      u32* q = (u32*)outx;
      const int base = ch * 36 + 8 * rw + 2 * quad;
      q[base] = (u32)bf16_rne(o[0]) | ((u32)bf16_rne(o[1]) << 16);
      q[base + 1] = (u32)bf16_rne(o[2]) | ((u32)bf16_rne(o[3]) << 16);
    }
  if (l15 == 0) {
#pragma unroll
    for (int r = 0; r < 4; r++)
      lpart[(size_t)blockIdx.x * 64 + 16 * w + 4 * quad + r] = lstate[r];
  }
  __syncthreads();
  {
    u16* od = Opart + (size_t)blockIdx.x * 16384;
    const int cr = tid >> 2, nch = (tid & 3) << 4;
#pragma unroll
    for (int it = 0; it < 4; it++) {
      const int c = cr + 64 * it;
      const u16* srcr = &outx[c * 72 + nch];
      uint4* dst = (uint4*)(od + c * 64 + nch);
      dst[0] = ((const uint4*)srcr)[0];
      dst[1] = ((const uint4*)srcr)[1];
    }
  }
}

// ------------- merge KV thirds: out = (O0+O1+O2)/(l0+l1+l2) -----------------
__global__ __launch_bounds__(256) void k_merge(const u16* __restrict__ Opart,
                                               const float* __restrict__ lpart,
                                               float* __restrict__ out) {
  const int idx = blockIdx.x * 256 + threadIdx.x;
  const int e4 = idx << 2;  // flat out index: b*2^20 + c*2^12 + n
  const int b = e4 >> 20;
  const int c = (e4 >> 12) & 255;
  const int n = e4 & 4095;
  const int qt = n >> 6, row = n & 63;
  const int g = (b * 64 + qt) * 3;
  const u16* q0 = Opart + (size_t)g * 16384 + c * 64 + row;
  ushort4 a0 = *(const ushort4*)q0;
  ushort4 a1 = *(const ushort4*)(q0 + 16384);
  ushort4 a2 = *(const ushort4*)(q0 + 32768);
  float4 l0 = *(const float4*)(lpart + (size_t)g * 64 + row);
  float4 l1 = *(const float4*)(lpart + (size_t)g * 64 + 64 + row);
  float4 l2 = *(const float4*)(lpart + (size_t)g * 64 + 128 + row);
  float4 o;
  o.x = (bf16_f(a0.x) + bf16_f(a1.x) + bf16_f(a2.x)) / (l0.x + l1.x + l2.x);
  o.y = (bf16_f(a0.y) + bf16_f(a1.y) + bf16_f(a2.y)) / (l0.y + l1.y + l2.y);
  o.z = (bf16_f(a0.z) + bf16_f(a1.z) + bf16_f(a2.z)) / (l0.z + l1.z + l2.z);
  o.w = (bf16_f(a0.w) + bf16_f(a1.w) + bf16_f(a2.w)) / (l0.w + l1.w + l2.w);
  *(float4*)(out + e4) = o;
}

extern "C" void kernel_launch(void* const* d_in, const int* in_sizes, int n_in,
                              void* d_out, int out_size, void* d_ws, size_t ws_size,
                              hipStream_t stream) {
  const float* p = (const float*)d_in[0];
  const float* bb = (const float*)d_in[1];
  const float* Wq = (const float*)d_in[2];
  const float* bq = (const float*)d_in[3];
  const float* Wk = (const float*)d_in[4];
  const float* bk = (const float*)d_in[5];
  float* out = (float*)d_out;

  const size_t plane = (size_t)B_ * N_ * O_;  // 2,097,152 u16
  u16* Qh = (u16*)d_ws;
  u16* Ql = Qh + plane;
  u16* Kh = Ql + plane;
  u16* Vbf = Kh + plane;                 // B*C*N u16 = 2 planes
  u16* Wqh = Vbf + 2 * plane;            // 4 x 32768 u16 = 256 KB
  u16* Wql = Wqh + 32768;
  u16* Wkh = Wql + 32768;
  u16* Wkl = Wkh + 32768;
  u16* Opart = Wkl + 32768;              // 768*16384 u16 = 25.2 MB
  float* lpart = (float*)(Opart + (size_t)768 * 16384);  // 768*64 fp32
  // total ws use ~= 46 MB

  hipLaunchKernelGGL(k_wprep, dim3(32), dim3(256), 0, stream, Wq, Wk, Wqh, Wql,
                     Wkh, Wkl);
  hipLaunchKernelGGL(k_proj, dim3(512), dim3(256), 0, stream, p, bb, bq, bk,
                     Wqh, Wql, Wkh, Wkl, Qh, Ql, Kh, Vbf);
  hipLaunchKernelGGL(k_flash, dim3(B_ * 64 * 3), dim3(256), 0, stream, Qh, Ql,
                     Kh, Vbf, Opart, lpart);
  hipLaunchKernelGGL(k_merge, dim3((B_ * C_ * N_) / (256 * 4)), dim3(256), 0,
                     stream, Opart, lpart, out);
}

// Round 9
// 207.152 us; speedup vs baseline: 1.0887x; 1.0887x over previous
//
#include <hip/hip_runtime.h>
#include <stdint.h>

// SpatialAttention: B=4, C_in=256, C_out=128, H=W=64 (N=4096)
// R9: bisect of R8's failure using validated parts. k_flash = R5's exact
// double-buffered kernel (passed twice, 98us). k_merge = R5's (validated).
// k_wprep = R7's (validated). The ONLY unvalidated piece is R8's k_proj
// (32-token blocks, grid 1024 = 4 blocks/CU, vectorized LDS staging, W from
// pre-split global planes). Pass -> R8 flash convicted; fail -> k_proj.

#define B_ 4
#define C_ 256
#define O_ 128
#define N_ 4096

#define AP 72  // proj LDS pitch (bf16 elems)
#define PP 40  // flash P-tile pitch (32 cols + pad)

typedef float v4f __attribute__((ext_vector_type(4)));
typedef short v8s __attribute__((ext_vector_type(8)));
typedef _Float16 v8h __attribute__((ext_vector_type(8)));
typedef uint32_t u32;
typedef unsigned short u16;

__device__ __forceinline__ u16 bf16_rne(float f) {
  u32 u = __builtin_bit_cast(u32, f);
  u += 0x7fffu + ((u >> 16) & 1u);
  return (u16)(u >> 16);
}
__device__ __forceinline__ float bf16_f(u16 s) {
  u32 u = ((u32)s) << 16;
  return __builtin_bit_cast(float, u);
}
__device__ __forceinline__ u16 f16_rne(float f) {
  _Float16 h = (_Float16)f;
  return __builtin_bit_cast(u16, h);
}
__device__ __forceinline__ float f16_f(u16 s) {
  return (float)__builtin_bit_cast(_Float16, s);
}
__device__ __forceinline__ v4f mfma16(v8s a, v8s b, v4f c) {
  return __builtin_amdgcn_mfma_f32_16x16x32_bf16(a, b, c, 0, 0, 0);
}
__device__ __forceinline__ v4f mfma16h(v8h a, v8h b, v4f c) {
  return __builtin_amdgcn_mfma_f32_16x16x32_f16(a, b, c, 0, 0, 0);
}
__device__ __forceinline__ void gl16(const u16* g, u16* l) {
  __builtin_amdgcn_global_load_lds(
      (const __attribute__((address_space(1))) u32*)g,
      (__attribute__((address_space(3))) u32*)l, 16, 0, 0);
}
template <int CTRL>
__device__ __forceinline__ float dppadd(float x) {
  int yi = __builtin_amdgcn_update_dpp(0, __builtin_bit_cast(int, x), CTRL,
                                       0xf, 0xf, true);
  return x + __builtin_bit_cast(float, yi);
}
__device__ __forceinline__ float sum16(float x) {
  x = dppadd<0xB1>(x);   // xor 1
  x = dppadd<0x4E>(x);   // xor 2
  x = dppadd<0x141>(x);  // xor 4 (row_half_mirror)
  x = dppadd<0x140>(x);  // xor 8 (row_mirror)
  return x;
}

// -------- W pre-split: fp32 [128][256] -> bf16 hi/lo planes (Wq and Wk) -----
// [validated R7]
__global__ __launch_bounds__(256) void k_wprep(const float* __restrict__ Wq,
                                               const float* __restrict__ Wk,
                                               u16* __restrict__ Wqh,
                                               u16* __restrict__ Wql,
                                               u16* __restrict__ Wkh,
                                               u16* __restrict__ Wkl) {
  const int inst = blockIdx.x >> 4;  // 16 blocks per matrix
  const float* src = inst ? Wk : Wq;
  u16* dh = inst ? Wkh : Wqh;
  u16* dl = inst ? Wkl : Wql;
  const int base = ((blockIdx.x & 15) * 256 + threadIdx.x) * 8;
  float4 a = ((const float4*)(src + base))[0];
  float4 c = ((const float4*)(src + base))[1];
  float v[8] = {a.x, a.y, a.z, a.w, c.x, c.y, c.z, c.w};
  u16 hh[8], ll[8];
#pragma unroll
  for (int j = 0; j < 8; j++) {
    hh[j] = bf16_rne(v[j]);
    ll[j] = bf16_rne(v[j] - bf16_f(hh[j]));
  }
  uint4 oh, ol;
  oh.x = (u32)hh[0] | ((u32)hh[1] << 16);
  oh.y = (u32)hh[2] | ((u32)hh[3] << 16);
  oh.z = (u32)hh[4] | ((u32)hh[5] << 16);
  oh.w = (u32)hh[6] | ((u32)hh[7] << 16);
  ol.x = (u32)ll[0] | ((u32)ll[1] << 16);
  ol.y = (u32)ll[2] | ((u32)ll[3] << 16);
  ol.z = (u32)ll[4] | ((u32)ll[5] << 16);
  ol.w = (u32)ll[6] | ((u32)ll[7] << 16);
  *(uint4*)(dh + base) = oh;
  *(uint4*)(dl + base) = ol;
}

// ------------- Q/K projection, 32-token blocks (grid 1024, 4 blocks/CU) -----
// [the one unvalidated kernel this round — R8's version]
__global__ __launch_bounds__(256, 4) void k_proj(
    const float* __restrict__ Xp, const float* __restrict__ Xb,
    const float* __restrict__ bq, const float* __restrict__ bk,
    const u16* __restrict__ Wqh, const u16* __restrict__ Wql,
    const u16* __restrict__ Wkh, const u16* __restrict__ Wkl,
    u16* __restrict__ Qh, u16* __restrict__ Ql, u16* __restrict__ Kh,
    u16* __restrict__ Vbf) {
  __shared__ __align__(16) short ah[32 * AP];
  __shared__ __align__(16) short al[32 * AP];
  const int tid = threadIdx.x;
  const int inst = blockIdx.x >> 9;  // block-uniform
  const float* X = inst ? Xb : Xp;
  const u16* Wh = inst ? Wkh : Wqh;
  const u16* Wl = inst ? Wkl : Wql;
  const float* bias = inst ? bk : bq;
  const int b = (blockIdx.x >> 7) & 3;
  const int n0 = (blockIdx.x & 127) << 5;
  const int w = tid >> 6, lane = tid & 63, l15 = lane & 15, quad = lane >> 4;
  const int rg = w & 1;   // row group: tokens n0+16*rg .. +15
  const int tq = w >> 1;  // output quad: to = 4*tq + i
  v4f acc[4];
#pragma unroll
  for (int t = 0; t < 4; t++) acc[t] = (v4f){0.f, 0.f, 0.f, 0.f};

  const int sn = tid & 31;  // staging token
  const int sg = tid >> 5;  // staging 8-channel group (0..7)

  for (int c0 = 0; c0 < C_; c0 += 64) {
    __syncthreads();
    {  // stage X^T tile [32 tok][64 c] split hi/lo (+ fused V cast on inst 1)
      const float* s = X + ((size_t)(b * C_ + c0 + sg * 8)) * N_ + n0 + sn;
      u16 hh[8], ll[8];
#pragma unroll
      for (int j = 0; j < 8; j++) {
        float v = s[(size_t)j * N_];
        hh[j] = bf16_rne(v);
        ll[j] = bf16_rne(v - bf16_f(hh[j]));
      }
      u32 ph[4], pl[4];
#pragma unroll
      for (int j = 0; j < 4; j++) {
        ph[j] = (u32)hh[2 * j] | ((u32)hh[2 * j + 1] << 16);
        pl[j] = (u32)ll[2 * j] | ((u32)ll[2 * j + 1] << 16);
      }
      *(uint4*)&ah[sn * AP + sg * 8] = make_uint4(ph[0], ph[1], ph[2], ph[3]);
      *(uint4*)&al[sn * AP + sg * 8] = make_uint4(pl[0], pl[1], pl[2], pl[3]);
      if (inst) {
#pragma unroll
        for (int j = 0; j < 8; j++)
          Vbf[((size_t)(b * C_ + c0 + sg * 8 + j)) * N_ + n0 + sn] = hh[j];
      }
    }
    __syncthreads();
#pragma unroll
    for (int s2 = 0; s2 < 2; s2++) {
      v8s a_h = *(const v8s*)&ah[(16 * rg + l15) * AP + 32 * s2 + 8 * quad];
      v8s a_l = *(const v8s*)&al[(16 * rg + l15) * AP + 32 * s2 + 8 * quad];
#pragma unroll
      for (int i = 0; i < 4; i++) {
        const size_t wo =
            (size_t)(16 * (4 * tq + i) + l15) * C_ + c0 + 32 * s2 + 8 * quad;
        v8s b_h = *(const v8s*)(Wh + wo);
        v8s b_l = *(const v8s*)(Wl + wo);
        acc[i] = mfma16(a_h, b_h, acc[i]);
        acc[i] = mfma16(a_h, b_l, acc[i]);
        acc[i] = mfma16(a_l, b_h, acc[i]);
      }
    }
  }
#pragma unroll
  for (int i = 0; i < 4; i++) {
    const int o = 16 * (4 * tq + i) + l15;
    const float bv = bias[o];
#pragma unroll
    for (int r = 0; r < 4; r++) {
      const int n = n0 + 16 * rg + 4 * quad + r;  // C/D row = quad*4+reg
      float v = acc[i][r] + bv;
      const size_t idx = (size_t)(b * N_ + n) * O_ + o;
      if (!inst) {
        u16 h = f16_rne(v);
        Qh[idx] = h;
        Ql[idx] = f16_rne(v - f16_f(h));
      } else {
        Kh[idx] = f16_rne(v);
      }
    }
  }
}

// ---------------- fused flash attention (partial over a KV half) ------------
// [VERBATIM R5 kernel — validated, 98us] double-buffered K/V, 2 barriers/iter,
// channel-split PV, no-max softmax, DPP row sums.
__global__ __launch_bounds__(256, 2) void k_flash(
    const u16* __restrict__ Qh, const u16* __restrict__ Ql,
    const u16* __restrict__ Khp, const u16* __restrict__ Vbf,
    u16* __restrict__ Opart, float* __restrict__ lpart) {
  // shorts: buf i at i*12288: K [32][128] fp16 @0, V [256][32] bf16 @4096
  //         P [64][PP] @24576
  __shared__ __align__(16) short smem[27136];  // 54272 B -> 2 blocks/CU
  short* Pt = smem + 24576;

  const int tid = threadIdx.x;
  const int w = tid >> 6, lane = tid & 63, l15 = lane & 15, quad = lane >> 4;
  const int h = blockIdx.x & 1;
  const int qt = (blockIdx.x >> 1) & 63;
  const int b = blockIdx.x >> 7;
  const int n0 = qt << 6;
  const int tok0 = h << 11;

  const u16* khb = Khp + (size_t)b * N_ * O_;
  const u16* vb = Vbf + (size_t)b * C_ * N_;
  short* pw = Pt + w * 16 * PP;

  // Q fragments (A-layout: row=lane&15, k=32s+8*quad+j), fp16 hi/lo
  v8h qh[4], ql[4];
  {
    const u16* qrh = Qh + (size_t)(b * N_ + n0 + 16 * w + l15) * O_;
    const u16* qrl = Ql + (size_t)(b * N_ + n0 + 16 * w + l15) * O_;
#pragma unroll
    for (int s = 0; s < 4; s++) {
      qh[s] = *(const v8h*)(qrh + 32 * s + 8 * quad);
      ql[s] = *(const v8h*)(qrl + 32 * s + 8 * quad);
    }
  }

  v4f oacc[16];  // [rw][cg]: rows 16rw+4quad+r, channels 64w+16cg+l15
#pragma unroll
  for (int t = 0; t < 16; t++) oacc[t] = (v4f){0.f, 0.f, 0.f, 0.f};
  float lstate[4] = {0.f, 0.f, 0.f, 0.f};

  auto stage = [&](int mtn, int bi) {
    const int m0n = tok0 + (mtn << 5);
    short* kd = smem + bi * 12288;
    short* vd = kd + 4096;
#pragma unroll
    for (int i = 0; i < 2; i++) {  // K fp16: 4 rows/issue, 8 rows/wave
      const int R = 8 * w + 4 * i;
      const int rl = R + (lane >> 4);
      const int cg = (lane & 15) ^ (rl & 15);
      gl16(khb + ((size_t)(m0n + rl) << 7) + (cg << 3), (u16*)(kd + (R << 7)));
    }
#pragma unroll
    for (int i = 0; i < 4; i++) {  // V bf16: 16 chan-rows/issue, 64/wave
      const int R = 64 * w + 16 * i;
      const int rl = R + (lane >> 2);
      const int cg = (lane & 3) ^ ((rl >> 1) & 3);
      gl16(vb + (size_t)rl * N_ + m0n + (cg << 3), (u16*)(vd + (R << 5)));
    }
  };

  stage(0, 0);

#pragma unroll 1
  for (int mt = 0; mt < 64; mt++) {
    const int pr = mt & 1;
    __syncthreads();  // B1: drains vmcnt(0) -> tile mt staged + visible
    if (mt + 1 < 64) stage(mt + 1, 1 - pr);
    const short* kc = smem + pr * 12288;
    const short* vc = kc + 4096;

    // QK: e = (qh+ql) . k, 2-pass fp16, two acc chains for ILP
    v4f eh[2], el[2];
#pragma unroll
    for (int t = 0; t < 2; t++) {
      eh[t] = (v4f){0.f, 0.f, 0.f, 0.f};
      el[t] = (v4f){0.f, 0.f, 0.f, 0.f};
    }
#pragma unroll
    for (int s = 0; s < 4; s++) {
#pragma unroll
      for (int t = 0; t < 2; t++) {
        const int off = ((16 * t + l15) << 7) + (((4 * s + quad) ^ l15) << 3);
        const v8h kf = *(const v8h*)&kc[off];
        eh[t] = mfma16h(qh[s], kf, eh[t]);
        el[t] = mfma16h(ql[s], kf, el[t]);
      }
    }

    // no-max softmax: p=exp(e); DPP 16-lane row sums; write P tile (shared)
#pragma unroll
    for (int r = 0; r < 4; r++) {
      float p0 = __expf(eh[0][r] + el[0][r]);
      float p1 = __expf(eh[1][r] + el[1][r]);
      lstate[r] += sum16(p0 + p1);
      pw[(4 * quad + r) * PP + l15] = (short)bf16_rne(p0);
      pw[(4 * quad + r) * PP + 16 + l15] = (short)bf16_rne(p1);
    }
    // B2: P handoff across waves (lgkm-only wait + raw barrier; the staged
    // prefetch vmcnt queue is NOT drained mid-iter)
    __builtin_amdgcn_s_waitcnt(0xC07F);  // lgkmcnt(0)
    asm volatile("s_barrier" ::: "memory");

    // PV channel-split: oacc[rw][cg] += P(rows 16rw) * V(ch 64w+16cg)
    v8s af[4];
#pragma unroll
    for (int rw = 0; rw < 4; rw++)
      af[rw] = *(const v8s*)&Pt[(16 * rw + l15) * PP + 8 * quad];
#pragma unroll
    for (int cg = 0; cg < 4; cg++) {
      const int ch = 64 * w + 16 * cg + l15;
      const int voff = (ch << 5) + ((quad ^ ((ch >> 1) & 3)) << 3);
      const v8s vf = *(const v8s*)&vc[voff];
#pragma unroll
      for (int rw = 0; rw < 4; rw++)
        oacc[rw * 4 + cg] = mfma16(af[rw], vf, oacc[rw * 4 + cg]);
    }
  }

  // epilogue: pack bf16 partial O into LDS [256][72], write l, copy out
  __syncthreads();
  u16* outx = (u16*)smem;  // pitch 72 shorts
#pragma unroll
  for (int rw = 0; rw < 4; rw++)
#pragma unroll
    for (int cg = 0; cg < 4; cg++) {
      const int ch = 64 * w + 16 * cg + l15;
      const v4f o = oacc[rw * 4 + cg];
      u32* q = (u32*)outx;
      const int base = ch * 36 + 8 * rw + 2 * quad;
      q[base] = (u32)bf16_rne(o[0]) | ((u32)bf16_rne(o[1]) << 16);
      q[base + 1] = (u32)bf16_rne(o[2]) | ((u32)bf16_rne(o[3]) << 16);
    }
  if (l15 == 0) {
#pragma unroll
    for (int r = 0; r < 4; r++)
      lpart[(size_t)blockIdx.x * 64 + 16 * w + 4 * quad + r] = lstate[r];
  }
  __syncthreads();
  {
    u16* od = Opart + (size_t)blockIdx.x * 16384;
    const int cr = tid >> 2, nch = (tid & 3) << 4;
#pragma unroll
    for (int it = 0; it < 4; it++) {
      const int c = cr + 64 * it;
      const u16* srcr = &outx[c * 72 + nch];
      uint4* dst = (uint4*)(od + c * 64 + nch);
      dst[0] = ((const uint4*)srcr)[0];
      dst[1] = ((const uint4*)srcr)[1];
    }
  }
}

// ---------------- merge KV halves: out = (O0+O1)/(l0+l1) --------------------
// [validated R5]
__global__ __launch_bounds__(256) void k_merge(const u16* __restrict__ Opart,
                                               const float* __restrict__ lpart,
                                               float* __restrict__ out) {
  const int idx = blockIdx.x * 256 + threadIdx.x;
  const int e4 = idx << 2;  // flat out index: b*2^20 + c*2^12 + n
  const int b = e4 >> 20;
  const int c = (e4 >> 12) & 255;
  const int n = e4 & 4095;
  const int qt = n >> 6, row = n & 63;
  const int g = (b * 64 + qt) * 2;
  const u16* q0 = Opart + (size_t)g * 16384 + c * 64 + row;
  ushort4 a0 = *(const ushort4*)q0;
  ushort4 a1 = *(const ushort4*)(q0 + 16384);
  float4 l0 = *(const float4*)(lpart + (size_t)g * 64 + row);
  float4 l1 = *(const float4*)(lpart + (size_t)g * 64 + 64 + row);
  float4 o;
  o.x = (bf16_f(a0.x) + bf16_f(a1.x)) / (l0.x + l1.x);
  o.y = (bf16_f(a0.y) + bf16_f(a1.y)) / (l0.y + l1.y);
  o.z = (bf16_f(a0.z) + bf16_f(a1.z)) / (l0.z + l1.z);
  o.w = (bf16_f(a0.w) + bf16_f(a1.w)) / (l0.w + l1.w);
  *(float4*)(out + e4) = o;
}

extern "C" void kernel_launch(void* const* d_in, const int* in_sizes, int n_in,
                              void* d_out, int out_size, void* d_ws, size_t ws_size,
                              hipStream_t stream) {
  const float* p = (const float*)d_in[0];
  const float* bb = (const float*)d_in[1];
  const float* Wq = (const float*)d_in[2];
  const float* bq = (const float*)d_in[3];
  const float* Wk = (const float*)d_in[4];
  const float* bk = (const float*)d_in[5];
  float* out = (float*)d_out;

  const size_t plane = (size_t)B_ * N_ * O_;  // 2,097,152 u16
  u16* Qh = (u16*)d_ws;
  u16* Ql = Qh + plane;
  u16* Kh = Ql + plane;
  u16* Vbf = Kh + plane;                 // B*C*N u16 = 2 planes
  u16* Wqh = Vbf + 2 * plane;            // 4 x 32768 u16 = 256 KB
  u16* Wql = Wqh + 32768;
  u16* Wkh = Wql + 32768;
  u16* Wkl = Wkh + 32768;
  u16* Opart = Wkl + 32768;              // 512*16384 u16 = 16.8 MB
  float* lpart = (float*)(Opart + (size_t)512 * 16384);  // 512*64 fp32
  // total ws use ~= 37.8 MB

  hipLaunchKernelGGL(k_wprep, dim3(32), dim3(256), 0, stream, Wq, Wk, Wqh, Wql,
                     Wkh, Wkl);
  hipLaunchKernelGGL(k_proj, dim3(1024), dim3(256), 0, stream, p, bb, bq, bk,
                     Wqh, Wql, Wkh, Wkl, Qh, Ql, Kh, Vbf);
  hipLaunchKernelGGL(k_flash, dim3(B_ * 64 * 2), dim3(256), 0, stream, Qh, Ql,
                     Kh, Vbf, Opart, lpart);
  hipLaunchKernelGGL(k_merge, dim3((B_ * C_ * N_) / (256 * 4)), dim3(256), 0,
                     stream, Opart, lpart, out);
}

// Round 10
// 202.534 us; speedup vs baseline: 1.1135x; 1.0228x over previous
//
#include <hip/hip_runtime.h>
#include <stdint.h>

// SpatialAttention: B=4, C_in=256, C_out=128, H=W=64 (N=4096)
// R10: 3 blocks/CU for real this time. R9 flash verbatim (double-buffered --
// single-buffer is empirically banned per R8) with exactly three diffs:
// (1) P pitch 40->32 => LDS = 53248 B = 26*2048, so even with a 2KB LDS
//     granule 3x53248 = 159744 <= 163840 (R7's 54272 rounded to 55296 and
//     missed -- that was R7's 2-blocks/CU mystery).
// (2) grid 768 = R7-validated KV thirds (tok0=h*1344, niter 42/42/44).
// (3) deferred row-sum: lstate accumulates per-lane; one sum16 at the end.
// proj/wprep = R9 (validated), merge = R7 3-partial (validated).

#define B_ 4
#define C_ 256
#define O_ 128
#define N_ 4096

#define AP 72  // proj LDS pitch (bf16 elems)
#define PP 32  // flash P-tile pitch (32 cols, no pad; LDS budget exact)

typedef float v4f __attribute__((ext_vector_type(4)));
typedef short v8s __attribute__((ext_vector_type(8)));
typedef _Float16 v8h __attribute__((ext_vector_type(8)));
typedef uint32_t u32;
typedef unsigned short u16;

__device__ __forceinline__ u16 bf16_rne(float f) {
  u32 u = __builtin_bit_cast(u32, f);
  u += 0x7fffu + ((u >> 16) & 1u);
  return (u16)(u >> 16);
}
__device__ __forceinline__ float bf16_f(u16 s) {
  u32 u = ((u32)s) << 16;
  return __builtin_bit_cast(float, u);
}
__device__ __forceinline__ u16 f16_rne(float f) {
  _Float16 h = (_Float16)f;
  return __builtin_bit_cast(u16, h);
}
__device__ __forceinline__ float f16_f(u16 s) {
  return (float)__builtin_bit_cast(_Float16, s);
}
__device__ __forceinline__ v4f mfma16(v8s a, v8s b, v4f c) {
  return __builtin_amdgcn_mfma_f32_16x16x32_bf16(a, b, c, 0, 0, 0);
}
__device__ __forceinline__ v4f mfma16h(v8h a, v8h b, v4f c) {
  return __builtin_amdgcn_mfma_f32_16x16x32_f16(a, b, c, 0, 0, 0);
}
__device__ __forceinline__ void gl16(const u16* g, u16* l) {
  __builtin_amdgcn_global_load_lds(
      (const __attribute__((address_space(1))) u32*)g,
      (__attribute__((address_space(3))) u32*)l, 16, 0, 0);
}
template <int CTRL>
__device__ __forceinline__ float dppadd(float x) {
  int yi = __builtin_amdgcn_update_dpp(0, __builtin_bit_cast(int, x), CTRL,
                                       0xf, 0xf, true);
  return x + __builtin_bit_cast(float, yi);
}
__device__ __forceinline__ float sum16(float x) {
  x = dppadd<0xB1>(x);   // xor 1
  x = dppadd<0x4E>(x);   // xor 2
  x = dppadd<0x141>(x);  // xor 4 (row_half_mirror)
  x = dppadd<0x140>(x);  // xor 8 (row_mirror)
  return x;
}

// -------- W pre-split: fp32 [128][256] -> bf16 hi/lo planes (Wq and Wk) -----
// [validated R7/R9]
__global__ __launch_bounds__(256) void k_wprep(const float* __restrict__ Wq,
                                               const float* __restrict__ Wk,
                                               u16* __restrict__ Wqh,
                                               u16* __restrict__ Wql,
                                               u16* __restrict__ Wkh,
                                               u16* __restrict__ Wkl) {
  const int inst = blockIdx.x >> 4;  // 16 blocks per matrix
  const float* src = inst ? Wk : Wq;
  u16* dh = inst ? Wkh : Wqh;
  u16* dl = inst ? Wkl : Wql;
  const int base = ((blockIdx.x & 15) * 256 + threadIdx.x) * 8;
  float4 a = ((const float4*)(src + base))[0];
  float4 c = ((const float4*)(src + base))[1];
  float v[8] = {a.x, a.y, a.z, a.w, c.x, c.y, c.z, c.w};
  u16 hh[8], ll[8];
#pragma unroll
  for (int j = 0; j < 8; j++) {
    hh[j] = bf16_rne(v[j]);
    ll[j] = bf16_rne(v[j] - bf16_f(hh[j]));
  }
  uint4 oh, ol;
  oh.x = (u32)hh[0] | ((u32)hh[1] << 16);
  oh.y = (u32)hh[2] | ((u32)hh[3] << 16);
  oh.z = (u32)hh[4] | ((u32)hh[5] << 16);
  oh.w = (u32)hh[6] | ((u32)hh[7] << 16);
  ol.x = (u32)ll[0] | ((u32)ll[1] << 16);
  ol.y = (u32)ll[2] | ((u32)ll[3] << 16);
  ol.z = (u32)ll[4] | ((u32)ll[5] << 16);
  ol.w = (u32)ll[6] | ((u32)ll[7] << 16);
  *(uint4*)(dh + base) = oh;
  *(uint4*)(dl + base) = ol;
}

// ------------- Q/K projection, 32-token blocks (grid 1024, 4 blocks/CU) -----
// [validated R9]
__global__ __launch_bounds__(256, 4) void k_proj(
    const float* __restrict__ Xp, const float* __restrict__ Xb,
    const float* __restrict__ bq, const float* __restrict__ bk,
    const u16* __restrict__ Wqh, const u16* __restrict__ Wql,
    const u16* __restrict__ Wkh, const u16* __restrict__ Wkl,
    u16* __restrict__ Qh, u16* __restrict__ Ql, u16* __restrict__ Kh,
    u16* __restrict__ Vbf) {
  __shared__ __align__(16) short ah[32 * AP];
  __shared__ __align__(16) short al[32 * AP];
  const int tid = threadIdx.x;
  const int inst = blockIdx.x >> 9;  // block-uniform
  const float* X = inst ? Xb : Xp;
  const u16* Wh = inst ? Wkh : Wqh;
  const u16* Wl = inst ? Wkl : Wql;
  const float* bias = inst ? bk : bq;
  const int b = (blockIdx.x >> 7) & 3;
  const int n0 = (blockIdx.x & 127) << 5;
  const int w = tid >> 6, lane = tid & 63, l15 = lane & 15, quad = lane >> 4;
  const int rg = w & 1;   // row group: tokens n0+16*rg .. +15
  const int tq = w >> 1;  // output quad: to = 4*tq + i
  v4f acc[4];
#pragma unroll
  for (int t = 0; t < 4; t++) acc[t] = (v4f){0.f, 0.f, 0.f, 0.f};

  const int sn = tid & 31;  // staging token
  const int sg = tid >> 5;  // staging 8-channel group (0..7)

  for (int c0 = 0; c0 < C_; c0 += 64) {
    __syncthreads();
    {  // stage X^T tile [32 tok][64 c] split hi/lo (+ fused V cast on inst 1)
      const float* s = X + ((size_t)(b * C_ + c0 + sg * 8)) * N_ + n0 + sn;
      u16 hh[8], ll[8];
#pragma unroll
      for (int j = 0; j < 8; j++) {
        float v = s[(size_t)j * N_];
        hh[j] = bf16_rne(v);
        ll[j] = bf16_rne(v - bf16_f(hh[j]));
      }
      u32 ph[4], pl[4];
#pragma unroll
      for (int j = 0; j < 4; j++) {
        ph[j] = (u32)hh[2 * j] | ((u32)hh[2 * j + 1] << 16);
        pl[j] = (u32)ll[2 * j] | ((u32)ll[2 * j + 1] << 16);
      }
      *(uint4*)&ah[sn * AP + sg * 8] = make_uint4(ph[0], ph[1], ph[2], ph[3]);
      *(uint4*)&al[sn * AP + sg * 8] = make_uint4(pl[0], pl[1], pl[2], pl[3]);
      if (inst) {
#pragma unroll
        for (int j = 0; j < 8; j++)
          Vbf[((size_t)(b * C_ + c0 + sg * 8 + j)) * N_ + n0 + sn] = hh[j];
      }
    }
    __syncthreads();
#pragma unroll
    for (int s2 = 0; s2 < 2; s2++) {
      v8s a_h = *(const v8s*)&ah[(16 * rg + l15) * AP + 32 * s2 + 8 * quad];
      v8s a_l = *(const v8s*)&al[(16 * rg + l15) * AP + 32 * s2 + 8 * quad];
#pragma unroll
      for (int i = 0; i < 4; i++) {
        const size_t wo =
            (size_t)(16 * (4 * tq + i) + l15) * C_ + c0 + 32 * s2 + 8 * quad;
        v8s b_h = *(const v8s*)(Wh + wo);
        v8s b_l = *(const v8s*)(Wl + wo);
        acc[i] = mfma16(a_h, b_h, acc[i]);
        acc[i] = mfma16(a_h, b_l, acc[i]);
        acc[i] = mfma16(a_l, b_h, acc[i]);
      }
    }
  }
#pragma unroll
  for (int i = 0; i < 4; i++) {
    const int o = 16 * (4 * tq + i) + l15;
    const float bv = bias[o];
#pragma unroll
    for (int r = 0; r < 4; r++) {
      const int n = n0 + 16 * rg + 4 * quad + r;  // C/D row = quad*4+reg
      float v = acc[i][r] + bv;
      const size_t idx = (size_t)(b * N_ + n) * O_ + o;
      if (!inst) {
        u16 h = f16_rne(v);
        Qh[idx] = h;
        Ql[idx] = f16_rne(v - f16_f(h));
      } else {
        Kh[idx] = f16_rne(v);
      }
    }
  }
}

// ---------------- fused flash attention (partial over a KV third) -----------
// R9's validated double-buffered kernel; diffs: PP 40->32 (LDS 53248B ->
// 3 blocks/CU under 2KB granule), KV thirds (R7-validated), deferred sum16.
__global__ __launch_bounds__(256, 3) void k_flash(
    const u16* __restrict__ Qh, const u16* __restrict__ Ql,
    const u16* __restrict__ Khp, const u16* __restrict__ Vbf,
    u16* __restrict__ Opart, float* __restrict__ lpart) {
  // shorts: buf i at i*12288: K [32][128] fp16 @0, V [256][32] bf16 @4096
  //         P [64][32] @24576 (2048)  => 26624 shorts = 53248 B
  __shared__ __align__(16) short smem[26624];
  short* Pt = smem + 24576;

  const int tid = threadIdx.x;
  const int w = tid >> 6, lane = tid & 63, l15 = lane & 15, quad = lane >> 4;
  const int bq = blockIdx.x / 3;
  const int h = blockIdx.x - bq * 3;
  const int qt = bq & 63;
  const int b = bq >> 6;
  const int n0 = qt << 6;
  const int tok0 = h * 1344;             // thirds: 1344/1344/1408 = 4096
  const int niter = (h == 2) ? 44 : 42;  // x32 tokens

  const u16* khb = Khp + (size_t)b * N_ * O_;
  const u16* vb = Vbf + (size_t)b * C_ * N_;
  short* pw = Pt + w * 16 * PP;

  // Q fragments (A-layout: row=lane&15, k=32s+8*quad+j), fp16 hi/lo
  v8h qh[4], ql[4];
  {
    const u16* qrh = Qh + (size_t)(b * N_ + n0 + 16 * w + l15) * O_;
    const u16* qrl = Ql + (size_t)(b * N_ + n0 + 16 * w + l15) * O_;
#pragma unroll
    for (int s = 0; s < 4; s++) {
      qh[s] = *(const v8h*)(qrh + 32 * s + 8 * quad);
      ql[s] = *(const v8h*)(qrl + 32 * s + 8 * quad);
    }
  }

  v4f oacc[16];  // [rw][cg]: rows 16rw+4quad+r, channels 64w+16cg+l15
#pragma unroll
  for (int t = 0; t < 16; t++) oacc[t] = (v4f){0.f, 0.f, 0.f, 0.f};
  float lstate[4] = {0.f, 0.f, 0.f, 0.f};  // per-lane partial (deferred sum16)

  auto stage = [&](int mtn, int bi) {
    const int m0n = tok0 + (mtn << 5);
    short* kd = smem + bi * 12288;
    short* vd = kd + 4096;
#pragma unroll
    for (int i = 0; i < 2; i++) {  // K fp16: 4 rows/issue, 8 rows/wave
      const int R = 8 * w + 4 * i;
      const int rl = R + (lane >> 4);
      const int cg = (lane & 15) ^ (rl & 15);
      gl16(khb + ((size_t)(m0n + rl) << 7) + (cg << 3), (u16*)(kd + (R << 7)));
    }
#pragma unroll
    for (int i = 0; i < 4; i++) {  // V bf16: 16 chan-rows/issue, 64/wave
      const int R = 64 * w + 16 * i;
      const int rl = R + (lane >> 2);
      const int cg = (lane & 3) ^ ((rl >> 1) & 3);
      gl16(vb + (size_t)rl * N_ + m0n + (cg << 3), (u16*)(vd + (R << 5)));
    }
  };

  stage(0, 0);

#pragma unroll 1
  for (int mt = 0; mt < niter; mt++) {
    const int pr = mt & 1;
    __syncthreads();  // B1: drains vmcnt(0) -> tile mt staged + visible
    if (mt + 1 < niter) stage(mt + 1, 1 - pr);
    const short* kc = smem + pr * 12288;
    const short* vc = kc + 4096;

    // QK: e = (qh+ql) . k, 2-pass fp16, two acc chains for ILP
    v4f eh[2], el[2];
#pragma unroll
    for (int t = 0; t < 2; t++) {
      eh[t] = (v4f){0.f, 0.f, 0.f, 0.f};
      el[t] = (v4f){0.f, 0.f, 0.f, 0.f};
    }
#pragma unroll
    for (int s = 0; s < 4; s++) {
#pragma unroll
      for (int t = 0; t < 2; t++) {
        const int off = ((16 * t + l15) << 7) + (((4 * s + quad) ^ l15) << 3);
        const v8h kf = *(const v8h*)&kc[off];
        eh[t] = mfma16h(qh[s], kf, eh[t]);
        el[t] = mfma16h(ql[s], kf, el[t]);
      }
    }

    // no-max softmax: p=exp(e); per-lane partial sums (sum16 deferred to end)
#pragma unroll
    for (int r = 0; r < 4; r++) {
      float p0 = __expf(eh[0][r] + el[0][r]);
      float p1 = __expf(eh[1][r] + el[1][r]);
      lstate[r] += p0 + p1;
      pw[(4 * quad + r) * PP + l15] = (short)bf16_rne(p0);
      pw[(4 * quad + r) * PP + 16 + l15] = (short)bf16_rne(p1);
    }
    // B2: P handoff across waves (lgkm-only wait + raw barrier; the staged
    // prefetch vmcnt queue is NOT drained mid-iter)
    __builtin_amdgcn_s_waitcnt(0xC07F);  // lgkmcnt(0)
    asm volatile("s_barrier" ::: "memory");

    // PV channel-split: oacc[rw][cg] += P(rows 16rw) * V(ch 64w+16cg)
    v8s af[4];
#pragma unroll
    for (int rw = 0; rw < 4; rw++)
      af[rw] = *(const v8s*)&Pt[(16 * rw + l15) * PP + 8 * quad];
#pragma unroll
    for (int cg = 0; cg < 4; cg++) {
      const int ch = 64 * w + 16 * cg + l15;
      const int voff = (ch << 5) + ((quad ^ ((ch >> 1) & 3)) << 3);
      const v8s vf = *(const v8s*)&vc[voff];
#pragma unroll
      for (int rw = 0; rw < 4; rw++)
        oacc[rw * 4 + cg] = mfma16(af[rw], vf, oacc[rw * 4 + cg]);
    }
  }

  // deferred 16-lane row sums, then write partial l
  float lsum[4];
#pragma unroll
  for (int r = 0; r < 4; r++) lsum[r] = sum16(lstate[r]);
  if (l15 == 0) {
#pragma unroll
    for (int r = 0; r < 4; r++)
      lpart[(size_t)blockIdx.x * 64 + 16 * w + 4 * quad + r] = lsum[r];
  }

  // epilogue: pack bf16 partial O into LDS [256][72], copy out
  __syncthreads();
  u16* outx = (u16*)smem;  // pitch 72 shorts = 18432 shorts, fits in 26624
#pragma unroll
  for (int rw = 0; rw < 4; rw++)
#pragma unroll
    for (int cg = 0; cg < 4; cg++) {
      const int ch = 64 * w + 16 * cg + l15;
      const v4f o = oacc[rw * 4 + cg];
      u32* q = (u32*)outx;
      const int base = ch * 36 + 8 * rw + 2 * quad;
      q[base] = (u32)bf16_rne(o[0]) | ((u32)bf16_rne(o[1]) << 16);
      q[base + 1] = (u32)bf16_rne(o[2]) | ((u32)bf16_rne(o[3]) << 16);
    }
  __syncthreads();
  {
    u16* od = Opart + (size_t)blockIdx.x * 16384;
    const int cr = tid >> 2, nch = (tid & 3) << 4;
#pragma unroll
    for (int it = 0; it < 4; it++) {
      const int c = cr + 64 * it;
      const u16* srcr = &outx[c * 72 + nch];
      uint4* dst = (uint4*)(od + c * 64 + nch);
      dst[0] = ((const uint4*)srcr)[0];
      dst[1] = ((const uint4*)srcr)[1];
    }
  }
}

// ------------- merge KV thirds: out = (O0+O1+O2)/(l0+l1+l2) -----------------
// [validated R7]
__global__ __launch_bounds__(256) void k_merge(const u16* __restrict__ Opart,
                                               const float* __restrict__ lpart,
                                               float* __restrict__ out) {
  const int idx = blockIdx.x * 256 + threadIdx.x;
  const int e4 = idx << 2;  // flat out index: b*2^20 + c*2^12 + n
  const int b = e4 >> 20;
  const int c = (e4 >> 12) & 255;
  const int n = e4 & 4095;
  const int qt = n >> 6, row = n & 63;
  const int g = (b * 64 + qt) * 3;
  const u16* q0 = Opart + (size_t)g * 16384 + c * 64 + row;
  ushort4 a0 = *(const ushort4*)q0;
  ushort4 a1 = *(const ushort4*)(q0 + 16384);
  ushort4 a2 = *(const ushort4*)(q0 + 32768);
  float4 l0 = *(const float4*)(lpart + (size_t)g * 64 + row);
  float4 l1 = *(const float4*)(lpart + (size_t)g * 64 + 64 + row);
  float4 l2 = *(const float4*)(lpart + (size_t)g * 64 + 128 + row);
  float4 o;
  o.x = (bf16_f(a0.x) + bf16_f(a1.x) + bf16_f(a2.x)) / (l0.x + l1.x + l2.x);
  o.y = (bf16_f(a0.y) + bf16_f(a1.y) + bf16_f(a2.y)) / (l0.y + l1.y + l2.y);
  o.z = (bf16_f(a0.z) + bf16_f(a1.z) + bf16_f(a2.z)) / (l0.z + l1.z + l2.z);
  o.w = (bf16_f(a0.w) + bf16_f(a1.w) + bf16_f(a2.w)) / (l0.w + l1.w + l2.w);
  *(float4*)(out + e4) = o;
}

extern "C" void kernel_launch(void* const* d_in, const int* in_sizes, int n_in,
                              void* d_out, int out_size, void* d_ws, size_t ws_size,
                              hipStream_t stream) {
  const float* p = (const float*)d_in[0];
  const float* bb = (const float*)d_in[1];
  const float* Wq = (const float*)d_in[2];
  const float* bq = (const float*)d_in[3];
  const float* Wk = (const float*)d_in[4];
  const float* bk = (const float*)d_in[5];
  float* out = (float*)d_out;

  const size_t plane = (size_t)B_ * N_ * O_;  // 2,097,152 u16
  u16* Qh = (u16*)d_ws;
  u16* Ql = Qh + plane;
  u16* Kh = Ql + plane;
  u16* Vbf = Kh + plane;                 // B*C*N u16 = 2 planes
  u16* Wqh = Vbf + 2 * plane;            // 4 x 32768 u16 = 256 KB
  u16* Wql = Wqh + 32768;
  u16* Wkh = Wql + 32768;
  u16* Wkl = Wkh + 32768;
  u16* Opart = Wkl + 32768;              // 768*16384 u16 = 25.2 MB
  float* lpart = (float*)(Opart + (size_t)768 * 16384);  // 768*64 fp32
  // total ws use ~= 46 MB

  hipLaunchKernelGGL(k_wprep, dim3(32), dim3(256), 0, stream, Wq, Wk, Wqh, Wql,
                     Wkh, Wkl);
  hipLaunchKernelGGL(k_proj, dim3(1024), dim3(256), 0, stream, p, bb, bq, bk,
                     Wqh, Wql, Wkh, Wkl, Qh, Ql, Kh, Vbf);
  hipLaunchKernelGGL(k_flash, dim3(B_ * 64 * 3), dim3(256), 0, stream, Qh, Ql,
                     Kh, Vbf, Opart, lpart);
  hipLaunchKernelGGL(k_merge, dim3((B_ * C_ * N_) / (256 * 4)), dim3(256), 0,
                     stream, Opart, lpart, out);
}